// Round 9
// baseline (274.953 us; speedup 1.0000x reference)
//
#include <hip/hip_runtime.h>
#include <hip/hip_bf16.h>
#include <math.h>

typedef unsigned int u32;
typedef unsigned short u16;
typedef __bf16 bf16x8 __attribute__((ext_vector_type(8)));
typedef float f32x4 __attribute__((ext_vector_type(4)));
typedef u32 u32x4 __attribute__((ext_vector_type(4)));
typedef u32 u32x2 __attribute__((ext_vector_type(2)));

#define T_DATA 500000
#define KNO    200          // T_no (kernel length)
#define SUB    20
#define E_NO   200
#define I_NO   50
#define NBAS   13
#define PI_F   3.14159265358979f
#define KKN    7            // conv K-tiles: 7*32 = 224 window
#define P_SZ   (T_DATA*SUB) // 10,000,000
#define MT_TOT (T_DATA/16)  // 31250
#define TCH    256
#define NCHUNKS_TOT ((T_DATA + TCH - 1)/TCH)   // 1954
#define GBLK   ((MT_TOT + 3)/4)                // 7813
#define ERB    264          // epi LDS row stride (u16), rotates banks by 4/row

__device__ __forceinline__ float bf2f(u16 v){
  union { u32 u; float f; } x; x.u = ((u32)v) << 16; return x.f;
}
__device__ __forceinline__ u16 f2bf(float f){
  union { float f; u32 u; } x; x.f = f;
  u32 u = x.u;
  return (u16)((u + 0x7FFFu + ((u >> 16) & 1u)) >> 16);
}
__device__ __forceinline__ u16 trunc_bf(float f){   // exact for 0.0/1.0 spikes
  union { float f; u32 u; } x; x.f = f;
  return (u16)(x.u >> 16);
}
__device__ __forceinline__ u32 f2u(float f){
  union { float f; u32 u; } x; x.f = f; return x.u;
}

// kernel-bank value k_{type,s}[j];  type: 0=e,1=i,2=spk,3=hist   (all params f32)
__device__ __forceinline__ float filt_val(int type, int s, int j,
    const float* Tau, const float* Del, const float* Wsyn,
    const float* Wspk, const float* Whist){
  if (type < 2){
    float tau = Tau[s*2+type];
    float del = Del[s*2+type];
    float w   = Wsyn[s*2+type];
    float t   = fmaxf((float)j - del, 0.0f);
    float tt  = t / (tau*tau);
    float v   = tt * expf(-tt) * (w*w);
    return (type == 1) ? -v : v;
  } else {
    const float* W = (type == 2) ? Wspk : Whist;
    float raw = 3.0f * logf((float)j + 1.0f);
    float acc = 0.0f;
#pragma unroll
    for (int b = 0; b < NBAS; b++){
      float d = raw - 0.5f*PI_F*(float)b;
      float bas = (d >= -PI_F && d <= PI_F) ? (0.5f*cosf(d) + 0.5f) : 0.0f;
      acc += W[s*NBAS + b] * bas;
    }
    return acc;
  }
}

// ---- K0 merged setup: filters tail (blocks 0..79), afrag (80..639), bfrag (640..679) ----
__global__ void k_setup(const float* Tau, const float* Del, const float* Wsyn,
                        const float* Wspk, const float* Whist,
                        const float* Ce, const float* Ci,
                        float* out, u16* afrag, u16* bfrag){
  int bid = blockIdx.x;
  int tid = threadIdx.x;
  if (bid < 80){
    int r = bid, type = r / SUB, s = r % SUB;
    for (int j = tid; j < KNO; j += 64)
      out[P_SZ + r*KNO + j] = filt_val(type, s, j, Tau, Del, Wsyn, Wspk, Whist);
  } else if (bid < 80 + 4*SUB*KKN){
    int b = bid - 80;
    int kk = b % KKN;
    int ts = b / KKN;
    int type = ts / SUB, s = ts % SUB;
    __shared__ float kf[KNO];
    for (int j = tid; j < KNO; j += 64)
      kf[j] = filt_val(type, s, j, Tau, Del, Wsyn, Wspk, Whist);
    __syncthreads();
    int l = tid;
    int m = l & 15, kg = l >> 4;
    int off = 200 - 32*kk;
    u32 p[4];
#pragma unroll
    for (int h = 0; h < 4; h++){
      int u0 = kg*8 + 2*h;
      int i0 = off + m - 1 - u0;
      int i1 = i0 - 1;
      u16 lo = (i0 >= 0 && i0 < KNO) ? f2bf(kf[i0]) : (u16)0;
      u16 hi = (i1 >= 0 && i1 < KNO) ? f2bf(kf[i1]) : (u16)0;
      p[h] = (u32)lo | ((u32)hi << 16);
    }
    u32* dst = (u32*)(afrag + (size_t)b*512 + l*8);
    dst[0]=p[0]; dst[1]=p[1]; dst[2]=p[2]; dst[3]=p[3];
  } else {
    const int NE = 2*7*512, NI = 2*2*512, NZ = 2*1*512;
    int b = bid - (80 + 4*SUB*KKN);               // 0..39
    for (int x = b*64 + tid; x < NE+NI+NZ; x += 40*64){
      int src, base, KT;
      if (x < NE){ src=0; base=x;       KT=7; }
      else if (x < NE+NI){ src=1; base=x-NE;    KT=2; }
      else {               src=2; base=x-NE-NI; KT=1; }
      int nt = base / (KT*512);
      int rem = base % (KT*512);
      int kt = rem / 512;
      int le = rem % 512;
      int l = le / 8, e = le % 8;
      int n = nt*16 + (l & 15);
      int k = kt*32 + (l >> 4)*8 + e;
      u16 v = 0;
      if (src == 0){ if (n < SUB && k < E_NO) v = trunc_bf(Ce[n*E_NO + k]); }
      else if (src == 1){ if (n < SUB && k < I_NO) v = trunc_bf(Ci[n*I_NO + k]); }
      else { if (n < SUB && k == n) v = trunc_bf(1.0f); }
      bfrag[x] = v;
    }
  }
}

// ---- K1: gather via MFMA with HOISTED loads + overfetch trim ----
template<int W, int KT>
__device__ __forceinline__ void gather_body(int bid, const float* __restrict__ src,
                                            const u16* __restrict__ bfrag,
                                            u16* __restrict__ dst){
  int wv = threadIdx.x >> 6, lane = threadIdx.x & 63;
  int mt = bid*4 + wv;
  if (mt >= MT_TOT) return;
  int t0 = mt*16;
  int m = lane & 15, kg = lane >> 4;
  const size_t NW = (size_t)T_DATA * W;

  u32 wb[KT][8];
#pragma unroll
  for (int kt = 0; kt < KT; kt++){
    // skip lanes whose whole 8-wide k-slice is >= W (B-frag is 0 there anyway)
    bool skip;
    if (W == 200)      skip = (kt == 6) && (kg > 0);
    else if (W == 50)  skip = (kt == 1) && (kg == 3);
    else               skip = (kg == 3);
    size_t cs = (size_t)(t0 + m)*W + kt*32 + kg*8;
    if (skip){
#pragma unroll
      for (int e = 0; e < 8; e++) wb[kt][e] = 0u;
    } else if (cs + 8 <= NW){
      if (W == 50){                        // rows only 8B-aligned
        *(u32x2*)&wb[kt][0] = *(const u32x2*)(src + cs);
        *(u32x2*)&wb[kt][2] = *(const u32x2*)(src + cs + 2);
        *(u32x2*)&wb[kt][4] = *(const u32x2*)(src + cs + 4);
        *(u32x2*)&wb[kt][6] = *(const u32x2*)(src + cs + 6);
      } else {                             // 16B-aligned (W=200, W=20)
        *(u32x4*)&wb[kt][0] = *(const u32x4*)(src + cs);
        *(u32x4*)&wb[kt][4] = *(const u32x4*)(src + cs + 4);
      }
    } else {
#pragma unroll
      for (int e = 0; e < 8; e++){
        size_t idx = cs + e;
        wb[kt][e] = (idx < NW) ? f2u(src[idx]) : 0u;
      }
    }
  }

  f32x4 acc0 = {0.f,0.f,0.f,0.f}, acc1 = {0.f,0.f,0.f,0.f};
#pragma unroll
  for (int kt = 0; kt < KT; kt++){
    union { bf16x8 v; u16 h[8]; } au;
#pragma unroll
    for (int e = 0; e < 8; e++) au.h[e] = (u16)(wb[kt][e] >> 16);
    bf16x8 b0 = *(const bf16x8*)(bfrag + kt*512 + lane*8);
    bf16x8 b1 = *(const bf16x8*)(bfrag + (KT + kt)*512 + lane*8);
    acc0 = __builtin_amdgcn_mfma_f32_16x16x32_bf16(au.v, b0, acc0, 0, 0, 0);
    acc1 = __builtin_amdgcn_mfma_f32_16x16x32_bf16(au.v, b1, acc1, 0, 0, 0);
  }
  int i0 = kg*4;   // C/D: t = 16*(lane&15) + 4*kg + reg ; channel = row block
  {
    u32 lo = (u32)f2bf(acc0[0]) | ((u32)f2bf(acc0[1]) << 16);
    u32 hi = (u32)f2bf(acc0[2]) | ((u32)f2bf(acc0[3]) << 16);
    u32* d = (u32*)(dst + (size_t)m*T_DATA + t0 + i0);
    d[0] = lo; d[1] = hi;
  }
  if (m < SUB - 16){
    u32 lo = (u32)f2bf(acc1[0]) | ((u32)f2bf(acc1[1]) << 16);
    u32 hi = (u32)f2bf(acc1[2]) | ((u32)f2bf(acc1[3]) << 16);
    u32* d = (u32*)(dst + (size_t)(16 + m)*T_DATA + t0 + i0);
    d[0] = lo; d[1] = hi;
  }
}

__global__ __launch_bounds__(256, 4) void k_gather_all(
    const float* __restrict__ S_e, const float* __restrict__ S_i,
    const float* __restrict__ Z, const u16* __restrict__ bfrag,
    u16* __restrict__ xe, u16* __restrict__ xi, u16* __restrict__ zt){
  int bid = blockIdx.x;
  if (bid < GBLK)            gather_body<200,7>(bid,          S_e, bfrag,                       xe);
  else if (bid < 2*GBLK)     gather_body<50, 2>(bid - GBLK,   S_i, bfrag + 2*7*512,             xi);
  else                       gather_body<20, 1>(bid - 2*GBLK, Z,   bfrag + 2*7*512 + 2*2*512,   zt);
}

// ---- shared load helper ----
template<bool G>
__device__ __forceinline__ bf16x8 loadw(const u16* __restrict__ row, long base){
  if (!G) return *(const bf16x8*)(row + base);
  union { bf16x8 v; u16 h[8]; } u;
#pragma unroll
  for (int e = 0; e < 8; e++){
    long idx = base + e;
    u.h[e] = (idx >= 0 && idx < T_DATA) ? row[idx] : (u16)0;
  }
  return u.v;
}

// ---- K2a: conv partials; pr layout CHUNK-LOCAL: pr[(c*80 + row)*TCH + tloc] ----
// rows: [0,20)=syn_e, [20,40)=syn_i, [40,60)=spk, [60,80)=hist
template<bool G>
__device__ __forceinline__ void convp_body(int type, int wv, int lane, int c,
    const u16* __restrict__ xe, const u16* __restrict__ xi,
    const u16* __restrict__ zt, const u16* __restrict__ afrag,
    u16* __restrict__ pr)
{
  int m = lane & 15, kg = lane >> 4;
  int boffB = 16*m + 8*kg;
  int toff  = 16*m + 4*kg;
  long wbase = (long)c*TCH - 200 + boffB;
  int ch0 = wv*5;
  size_t cbase = (size_t)c*80*TCH;

  if (type < 2){
    const u16* xs = (type == 0) ? xe : xi;
#pragma unroll
    for (int q = 0; q < 5; q++){
      int ch = ch0 + q;
      const u16* row = xs + (size_t)ch*T_DATA;
      const u16* aa  = afrag + (size_t)((type*SUB + ch)*KKN)*512 + lane*8;
      bf16x8 b[KKN];
#pragma unroll
      for (int kk = 0; kk < KKN; kk++) b[kk] = loadw<G>(row, wbase + 32*kk);
      f32x4 a = {0.f,0.f,0.f,0.f};
#pragma unroll
      for (int kk = 0; kk < KKN; kk++)
        a = __builtin_amdgcn_mfma_f32_16x16x32_bf16(*(const bf16x8*)(aa + kk*512), b[kk], a, 0,0,0);
      u32* d = (u32*)(pr + cbase + (size_t)(type*SUB + ch)*TCH + toff);
      d[0] = (u32)f2bf(a[0]) | ((u32)f2bf(a[1]) << 16);
      d[1] = (u32)f2bf(a[2]) | ((u32)f2bf(a[3]) << 16);
    }
  } else {
#pragma unroll
    for (int q = 0; q < 5; q++){
      int ch = ch0 + q;
      const u16* row = zt + (size_t)ch*T_DATA;
      const u16* a2  = afrag + (size_t)((2*SUB + ch)*KKN)*512 + lane*8;
      const u16* a3  = afrag + (size_t)((3*SUB + ch)*KKN)*512 + lane*8;
      bf16x8 b[KKN];
#pragma unroll
      for (int kk = 0; kk < KKN; kk++) b[kk] = loadw<G>(row, wbase + 32*kk);
      f32x4 s = {0.f,0.f,0.f,0.f}, h = {0.f,0.f,0.f,0.f};
#pragma unroll
      for (int kk = 0; kk < KKN; kk++){
        s = __builtin_amdgcn_mfma_f32_16x16x32_bf16(*(const bf16x8*)(a2 + kk*512), b[kk], s, 0,0,0);
        h = __builtin_amdgcn_mfma_f32_16x16x32_bf16(*(const bf16x8*)(a3 + kk*512), b[kk], h, 0,0,0);
      }
      u32* d1 = (u32*)(pr + cbase + (size_t)(2*SUB + ch)*TCH + toff);
      d1[0] = (u32)f2bf(s[0]) | ((u32)f2bf(s[1]) << 16);
      d1[1] = (u32)f2bf(s[2]) | ((u32)f2bf(s[3]) << 16);
      u32* d2 = (u32*)(pr + cbase + (size_t)(3*SUB + ch)*TCH + toff);
      d2[0] = (u32)f2bf(h[0]) | ((u32)f2bf(h[1]) << 16);
      d2[1] = (u32)f2bf(h[2]) | ((u32)f2bf(h[3]) << 16);
    }
  }
}

__global__ __launch_bounds__(256, 4) void k_convp(
    const u16* __restrict__ xe, const u16* __restrict__ xi,
    const u16* __restrict__ zt, const u16* __restrict__ afrag,
    u16* __restrict__ pr)
{
  int bid = blockIdx.x;
  int type = bid / NCHUNKS_TOT;
  int cb = bid - type*NCHUNKS_TOT;
  // bijective XCD-aware chunk swizzle within each type
  int xcd = cb & 7, sb = cb >> 3;
  const int q8 = NCHUNKS_TOT >> 3, r8 = NCHUNKS_TOT & 7;   // 244, 2
  int c = (xcd < r8 ? xcd*(q8+1) : r8*(q8+1) + (xcd-r8)*q8) + sb;
  int wv = threadIdx.x >> 6, lane = threadIdx.x & 63;
  if (c > 0 && c < NCHUNKS_TOT-1)
    convp_body<false>(type, wv, lane, c, xe, xi, zt, afrag, pr);
  else
    convp_body<true >(type, wv, lane, c, xe, xi, zt, afrag, pr);
}

// ---- K2b: epilogue per chunk: LDS-stage 80x256 slab, mix + sigmoid, float4 out ----
__global__ __launch_bounds__(256, 3) void k_epi(
    const u16* __restrict__ pr, const float* __restrict__ Cden,
    const float* __restrict__ Theta, float* __restrict__ out)
{
  __shared__ __align__(16) u16 lsd[80*ERB];        // 42,240 B (reused as pbuf)
  __shared__ float lcden[SUB*SUB];
  __shared__ float lth[SUB];
  float* pbuf = (float*)lsd;                       // overlay after sync

  int tid = threadIdx.x;
  // FIX (R8 bug): strided loads — 256 threads must cover all 400+20 params
  for (int i = tid; i < SUB*SUB; i += 256) lcden[i] = Cden[i];
  if (tid < SUB) lth[tid] = Theta[tid];

  int c = blockIdx.x;
  const u16* src = pr + (size_t)c*80*TCH;
  // coalesced stage: 80 rows x 256 cols bf16 -> LDS (bank-rotated stride)
  for (int i = tid; i < 80*32; i += 256){
    int row = i >> 5, col8 = (i & 31)*8;
    *(bf16x8*)(lsd + row*ERB + col8) = *(const bf16x8*)(src + row*TCH + col8);
  }
  __syncthreads();

  int t = tid;
  float spv[SUB];
#pragma unroll
  for (int s = 0; s < SUB; s++) spv[s] = bf2f(lsd[(2*SUB + s)*ERB + t]);
  float res[SUB];
#pragma unroll
  for (int sp = 0; sp < SUB; sp++){
    float msum = bf2f(lsd[sp*ERB + t]) + bf2f(lsd[(SUB + sp)*ERB + t])
               + lth[sp] + bf2f(lsd[(3*SUB + sp)*ERB + t]);
#pragma unroll
    for (int u = 0; u < SUB; u++) msum += lcden[sp*SUB + u] * spv[u];
    res[sp] = 1.0f/(1.0f + expf(-msum));
  }
  __syncthreads();               // all lsd reads complete before overlay
#pragma unroll
  for (int sp = 0; sp < SUB; sp++) pbuf[t*21 + sp] = res[sp];
  __syncthreads();

  long t0 = (long)c*TCH;
  int tv = (int)min((long)TCH, (long)(T_DATA - t0));
  int np4 = tv*SUB/4;
  for (int i = tid; i < np4; i += 256){
    int p = i*4;
    int tt = p/20, sp = p - tt*20;
    float4 v;
    v.x = pbuf[tt*21 + sp];   v.y = pbuf[tt*21 + sp+1];
    v.z = pbuf[tt*21 + sp+2]; v.w = pbuf[tt*21 + sp+3];
    *(float4*)(out + (size_t)t0*SUB + p) = v;
  }
}

// ---- FALLBACK (R6 fused conv) if ws is too small for partials ----
template<bool G>
__device__ __forceinline__ void conv_mfma(int wv, int lane, int c,
    const u16* __restrict__ xe, const u16* __restrict__ xi,
    const u16* __restrict__ zt, const u16* __restrict__ afrag, u16* rr)
{
  int m = lane & 15, kg = lane >> 4;
  int boffB = 16*m + 8*kg;
  int toff  = 16*m + 4*kg;
  long wbase = (long)c*TCH - 200 + boffB;

  if (wv < 4){
    int ch0 = wv*5;
    f32x4 acc[5];
#pragma unroll
    for (int q = 0; q < 5; q++){
      int ch = ch0 + q;
      const u16* rowE = xe + (size_t)ch*T_DATA;
      const u16* rowI = xi + (size_t)ch*T_DATA;
      const u16* ae = afrag + (size_t)((0*SUB + ch)*KKN)*512 + lane*8;
      const u16* ai = afrag + (size_t)((1*SUB + ch)*KKN)*512 + lane*8;
      bf16x8 be[KKN], bi[KKN];
#pragma unroll
      for (int kk = 0; kk < KKN; kk++) be[kk] = loadw<G>(rowE, wbase + 32*kk);
#pragma unroll
      for (int kk = 0; kk < KKN; kk++) bi[kk] = loadw<G>(rowI, wbase + 32*kk);
      f32x4 a = {0.f,0.f,0.f,0.f};
#pragma unroll
      for (int kk = 0; kk < KKN; kk++){
        a = __builtin_amdgcn_mfma_f32_16x16x32_bf16(*(const bf16x8*)(ae + kk*512), be[kk], a, 0,0,0);
        a = __builtin_amdgcn_mfma_f32_16x16x32_bf16(*(const bf16x8*)(ai + kk*512), bi[kk], a, 0,0,0);
      }
      acc[q] = a;
    }
#pragma unroll
    for (int q = 0; q < 5; q++){
      int ch = ch0 + q;
      u32* d = (u32*)(rr + ch*TCH + toff);
      d[0] = (u32)f2bf(acc[q][0]) | ((u32)f2bf(acc[q][1]) << 16);
      d[1] = (u32)f2bf(acc[q][2]) | ((u32)f2bf(acc[q][3]) << 16);
    }
  } else {
    int ch0 = (wv - 4)*5;
    f32x4 as[5], ah[5];
#pragma unroll
    for (int q = 0; q < 5; q++){
      int ch = ch0 + q;
      const u16* rowZ = zt + (size_t)ch*T_DATA;
      const u16* a2 = afrag + (size_t)((2*SUB + ch)*KKN)*512 + lane*8;
      const u16* a3 = afrag + (size_t)((3*SUB + ch)*KKN)*512 + lane*8;
      bf16x8 bz[KKN];
#pragma unroll
      for (int kk = 0; kk < KKN; kk++) bz[kk] = loadw<G>(rowZ, wbase + 32*kk);
      f32x4 s = {0.f,0.f,0.f,0.f}, h = {0.f,0.f,0.f,0.f};
#pragma unroll
      for (int kk = 0; kk < KKN; kk++){
        s = __builtin_amdgcn_mfma_f32_16x16x32_bf16(*(const bf16x8*)(a2 + kk*512), bz[kk], s, 0,0,0);
        h = __builtin_amdgcn_mfma_f32_16x16x32_bf16(*(const bf16x8*)(a3 + kk*512), bz[kk], h, 0,0,0);
      }
      as[q] = s; ah[q] = h;
    }
#pragma unroll
    for (int q = 0; q < 5; q++){
      int ch = ch0 + q;
      u32* d1 = (u32*)(rr + (SUB + ch)*TCH + toff);
      d1[0] = (u32)f2bf(as[q][0]) | ((u32)f2bf(as[q][1]) << 16);
      d1[1] = (u32)f2bf(as[q][2]) | ((u32)f2bf(as[q][3]) << 16);
      u32* d2 = (u32*)(rr + (2*SUB + ch)*TCH + toff);
      d2[0] = (u32)f2bf(ah[q][0]) | ((u32)f2bf(ah[q][1]) << 16);
      d2[1] = (u32)f2bf(ah[q][2]) | ((u32)f2bf(ah[q][3]) << 16);
    }
  }
}

__global__ __launch_bounds__(512, 4) void k_conv(
    const u16* __restrict__ xe, const u16* __restrict__ xi,
    const u16* __restrict__ zt, const u16* __restrict__ afrag,
    const float* __restrict__ Cden, const float* __restrict__ Theta,
    float* __restrict__ out)
{
  __shared__ __align__(16) u16 rr[3*SUB*TCH];
  __shared__ float lcden[SUB*SUB];
  __shared__ float lth[SUB];
  float* pbuf = (float*)rr;

  int tid = threadIdx.x;
  if (tid < SUB*SUB) lcden[tid] = Cden[tid];
  else if (tid < SUB*SUB + SUB) lth[tid - SUB*SUB] = Theta[tid - SUB*SUB];

  int bid = blockIdx.x;
  int xcd = bid & 7, sb = bid >> 3;
  const int q8 = NCHUNKS_TOT >> 3, r8 = NCHUNKS_TOT & 7;
  int c = (xcd < r8 ? xcd*(q8+1) : r8*(q8+1) + (xcd-r8)*q8) + sb;

  int wv = tid >> 6, lane = tid & 63;
  if (c > 0 && c < NCHUNKS_TOT-1)
    conv_mfma<false>(wv, lane, c, xe, xi, zt, afrag, rr);
  else
    conv_mfma<true >(wv, lane, c, xe, xi, zt, afrag, rr);
  __syncthreads();

  int t = tid >> 1, h = tid & 1;
  float spkv[SUB];
#pragma unroll
  for (int s = 0; s < SUB; s++) spkv[s] = bf2f(rr[(SUB + s)*TCH + t]);
  float res[10];
#pragma unroll
  for (int j = 0; j < 10; j++){
    int sp = h*10 + j;
    float msum = bf2f(rr[sp*TCH + t]) + lth[sp] + bf2f(rr[(2*SUB + sp)*TCH + t]);
#pragma unroll
    for (int s = 0; s < SUB; s++) msum += lcden[sp*SUB + s] * spkv[s];
    res[j] = 1.0f/(1.0f + expf(-msum));
  }
  __syncthreads();
#pragma unroll
  for (int j = 0; j < 10; j++) pbuf[t*21 + h*10 + j] = res[j];
  __syncthreads();

  int t0c = c*TCH;
  int tv = min(TCH, T_DATA - t0c);
  int np4 = tv*SUB/4;
  for (int i = tid; i < np4; i += 512){
    int p = i*4;
    int tt = p/20, sp = p - tt*20;
    float4 v;
    v.x = pbuf[tt*21 + sp];   v.y = pbuf[tt*21 + sp+1];
    v.z = pbuf[tt*21 + sp+2]; v.w = pbuf[tt*21 + sp+3];
    *(float4*)(out + (size_t)t0c*SUB + p) = v;
  }
}

extern "C" void kernel_launch(void* const* d_in, const int* in_sizes, int n_in,
                              void* d_out, int out_size, void* d_ws, size_t ws_size,
                              hipStream_t stream){
  const float* S_e  = (const float*)d_in[0];
  const float* S_i  = (const float*)d_in[1];
  const float* Z    = (const float*)d_in[2];
  const float* Cden = (const float*)d_in[3];
  const float* C_e  = (const float*)d_in[4];
  const float* C_i  = (const float*)d_in[5];
  const float* Tau  = (const float*)d_in[6];
  const float* Del  = (const float*)d_in[7];
  const float* Wsyn = (const float*)d_in[8];
  const float* Wspk = (const float*)d_in[9];
  const float* Whist= (const float*)d_in[10];
  const float* Theta= (const float*)d_in[11];
  float* out = (float*)d_out;

  // workspace layout (bf16 elements); prefix identical to prior passing rounds
  u16* xe    = (u16*)d_ws;
  u16* xi    = xe + (size_t)SUB*T_DATA;
  u16* zt    = xi + (size_t)SUB*T_DATA;
  u16* afrag = zt + (size_t)SUB*T_DATA;            // 4*20*7*512 = 286720
  u16* bfrag = afrag + (size_t)4*SUB*KKN*512;      // 10240
  u16* pr    = bfrag + 10240;                      // NCHUNKS*80*TCH chunk-local partials
  size_t need_old = ((size_t)3*SUB*T_DATA + (size_t)4*SUB*KKN*512 + 10240) * 2;
  size_t need_new = need_old + (size_t)NCHUNKS_TOT*80*TCH*2;
  if (ws_size < need_old) return;   // ~60.6 MB minimum

  k_setup<<<80 + 4*SUB*KKN + 40, 64, 0, stream>>>(
      Tau, Del, Wsyn, Wspk, Whist, C_e, C_i, out, afrag, bfrag);

  k_gather_all<<<3*GBLK, 256, 0, stream>>>(S_e, S_i, Z, bfrag, xe, xi, zt);

  if (ws_size >= need_new){
    k_convp<<<3*NCHUNKS_TOT, 256, 0, stream>>>(xe, xi, zt, afrag, pr);
    k_epi<<<NCHUNKS_TOT, 256, 0, stream>>>(pr, Cden, Theta, out);
  } else {
    k_conv<<<NCHUNKS_TOT, 512, 0, stream>>>(xe, xi, zt, afrag, Cden, Theta, out);
  }
}

// Round 10
// 225.831 us; speedup vs baseline: 1.2175x; 1.2175x over previous
//
#include <hip/hip_runtime.h>
#include <hip/hip_bf16.h>
#include <math.h>

typedef unsigned int u32;
typedef unsigned short u16;
typedef __bf16 bf16x8 __attribute__((ext_vector_type(8)));
typedef float f32x4 __attribute__((ext_vector_type(4)));
typedef u32 u32x4 __attribute__((ext_vector_type(4)));
typedef u32 u32x2 __attribute__((ext_vector_type(2)));

#define T_DATA 500000
#define KNO    200          // T_no (kernel length)
#define SUB    20
#define E_NO   200
#define I_NO   50
#define NBAS   13
#define PI_F   3.14159265358979f
#define KKN    7            // conv K-tiles: 7*32 = 224 window
#define P_SZ   (T_DATA*SUB) // 10,000,000
#define TCH    256
#define NCHUNKS_TOT ((T_DATA + TCH - 1)/TCH)   // 1954
#define NST    29           // gather strips per window: 29*16 = 464
#define WSTR   472          // LDS window row stride (u16); 944B -> ch-step = 12 banks

__device__ __forceinline__ float bf2f(u16 v){
  union { u32 u; float f; } x; x.u = ((u32)v) << 16; return x.f;
}
__device__ __forceinline__ u16 f2bf(float f){
  union { float f; u32 u; } x; x.f = f;
  u32 u = x.u;
  return (u16)((u + 0x7FFFu + ((u >> 16) & 1u)) >> 16);
}
__device__ __forceinline__ u16 trunc_bf(float f){   // exact for 0.0/1.0 spikes
  union { float f; u32 u; } x; x.f = f;
  return (u16)(x.u >> 16);
}
__device__ __forceinline__ u32 f2u(float f){
  union { float f; u32 u; } x; x.f = f; return x.u;
}

// kernel-bank value k_{type,s}[j];  type: 0=e,1=i,2=spk,3=hist   (all params f32)
__device__ __forceinline__ float filt_val(int type, int s, int j,
    const float* Tau, const float* Del, const float* Wsyn,
    const float* Wspk, const float* Whist){
  if (type < 2){
    float tau = Tau[s*2+type];
    float del = Del[s*2+type];
    float w   = Wsyn[s*2+type];
    float t   = fmaxf((float)j - del, 0.0f);
    float tt  = t / (tau*tau);
    float v   = tt * expf(-tt) * (w*w);
    return (type == 1) ? -v : v;
  } else {
    const float* W = (type == 2) ? Wspk : Whist;
    float raw = 3.0f * logf((float)j + 1.0f);
    float acc = 0.0f;
#pragma unroll
    for (int b = 0; b < NBAS; b++){
      float d = raw - 0.5f*PI_F*(float)b;
      float bas = (d >= -PI_F && d <= PI_F) ? (0.5f*cosf(d) + 0.5f) : 0.0f;
      acc += W[s*NBAS + b] * bas;
    }
    return acc;
  }
}

// ---- K0 merged setup: filters tail (blocks 0..79), afrag (80..639), bfrag (640..679) ----
__global__ void k_setup(const float* Tau, const float* Del, const float* Wsyn,
                        const float* Wspk, const float* Whist,
                        const float* Ce, const float* Ci,
                        float* out, u16* afrag, u16* bfrag){
  int bid = blockIdx.x;
  int tid = threadIdx.x;
  if (bid < 80){
    int r = bid, type = r / SUB, s = r % SUB;
    for (int j = tid; j < KNO; j += 64)
      out[P_SZ + r*KNO + j] = filt_val(type, s, j, Tau, Del, Wsyn, Wspk, Whist);
  } else if (bid < 80 + 4*SUB*KKN){
    int b = bid - 80;
    int kk = b % KKN;
    int ts = b / KKN;
    int type = ts / SUB, s = ts % SUB;
    __shared__ float kf[KNO];
    for (int j = tid; j < KNO; j += 64)
      kf[j] = filt_val(type, s, j, Tau, Del, Wsyn, Wspk, Whist);
    __syncthreads();
    int l = tid;
    int m = l & 15, kg = l >> 4;
    int off = 200 - 32*kk;
    u32 p[4];
#pragma unroll
    for (int h = 0; h < 4; h++){
      int u0 = kg*8 + 2*h;
      int i0 = off + m - 1 - u0;
      int i1 = i0 - 1;
      u16 lo = (i0 >= 0 && i0 < KNO) ? f2bf(kf[i0]) : (u16)0;
      u16 hi = (i1 >= 0 && i1 < KNO) ? f2bf(kf[i1]) : (u16)0;
      p[h] = (u32)lo | ((u32)hi << 16);
    }
    u32* dst = (u32*)(afrag + (size_t)b*512 + l*8);
    dst[0]=p[0]; dst[1]=p[1]; dst[2]=p[2]; dst[3]=p[3];
  } else {
    const int NE = 2*7*512, NI = 2*2*512, NZ = 2*1*512;
    int b = bid - (80 + 4*SUB*KKN);               // 0..39
    for (int x = b*64 + tid; x < NE+NI+NZ; x += 40*64){
      int src, base, KT;
      if (x < NE){ src=0; base=x;       KT=7; }
      else if (x < NE+NI){ src=1; base=x-NE;    KT=2; }
      else {               src=2; base=x-NE-NI; KT=1; }
      int nt = base / (KT*512);
      int rem = base % (KT*512);
      int kt = rem / 512;
      int le = rem % 512;
      int l = le / 8, e = le % 8;
      int n = nt*16 + (l & 15);
      int k = kt*32 + (l >> 4)*8 + e;
      u16 v = 0;
      if (src == 0){ if (n < SUB && k < E_NO) v = trunc_bf(Ce[n*E_NO + k]); }
      else if (src == 1){ if (n < SUB && k < I_NO) v = trunc_bf(Ci[n*I_NO + k]); }
      else { if (n < SUB && k == n) v = trunc_bf(1.0f); }
      bfrag[x] = v;
    }
  }
}

// ---- stage-1 helper: gather one array's window into LDS via MFMA ----
// wrow = win + arr*SUB*WSTR ; window local t in [0, 464) maps to global tw0 + local
template<int W, int KT>
__device__ __forceinline__ void stage1(const float* __restrict__ src,
                                       const u16* __restrict__ bfr,
                                       u16* __restrict__ wrow,
                                       long tw0, int wv, int lane){
  int m = lane & 15, kg = lane >> 4;
  const size_t NW = (size_t)T_DATA * W;
  for (int s = wv; s < NST; s += 8){
    long tr = tw0 + s*16 + m;                 // global A-row; may be <0 or >=T_DATA
    u32 wb[KT][8];
#pragma unroll
    for (int kt = 0; kt < KT; kt++){
      bool skip;                              // whole 8-wide k-slice >= W (B-frag is 0)
      if (W == 200)      skip = (kt == 6) && (kg > 0);
      else if (W == 50)  skip = (kt == 1) && (kg == 3);
      else               skip = (kg == 3);
      if (skip || tr < 0 || tr >= T_DATA){
#pragma unroll
        for (int e = 0; e < 8; e++) wb[kt][e] = 0u;
      } else {
        size_t cs = (size_t)tr*W + kt*32 + kg*8;
        if (cs + 8 <= NW){
          if (W == 50){                        // rows only 8B-aligned
            *(u32x2*)&wb[kt][0] = *(const u32x2*)(src + cs);
            *(u32x2*)&wb[kt][2] = *(const u32x2*)(src + cs + 2);
            *(u32x2*)&wb[kt][4] = *(const u32x2*)(src + cs + 4);
            *(u32x2*)&wb[kt][6] = *(const u32x2*)(src + cs + 6);
          } else {                             // 16B-aligned (W=200, W=20)
            *(u32x4*)&wb[kt][0] = *(const u32x4*)(src + cs);
            *(u32x4*)&wb[kt][4] = *(const u32x4*)(src + cs + 4);
          }
        } else {
#pragma unroll
          for (int e = 0; e < 8; e++){
            size_t idx = cs + e;
            wb[kt][e] = (idx < NW) ? f2u(src[idx]) : 0u;
          }
        }
      }
    }
    f32x4 acc0 = {0.f,0.f,0.f,0.f}, acc1 = {0.f,0.f,0.f,0.f};
#pragma unroll
    for (int kt = 0; kt < KT; kt++){
      union { bf16x8 v; u16 h[8]; } au;
#pragma unroll
      for (int e = 0; e < 8; e++) au.h[e] = (u16)(wb[kt][e] >> 16);
      bf16x8 b0 = *(const bf16x8*)(bfr + kt*512 + lane*8);
      bf16x8 b1 = *(const bf16x8*)(bfr + (KT + kt)*512 + lane*8);
      acc0 = __builtin_amdgcn_mfma_f32_16x16x32_bf16(au.v, b0, acc0, 0, 0, 0);
      acc1 = __builtin_amdgcn_mfma_f32_16x16x32_bf16(au.v, b1, acc1, 0, 0, 0);
    }
    int i0 = s*16 + kg*4;                     // window-local t; C/D row = 4*kg+reg
    {
      u32* d = (u32*)(wrow + (size_t)m*WSTR + i0);        // channel = col = lane&15
      d[0] = (u32)f2bf(acc0[0]) | ((u32)f2bf(acc0[1]) << 16);
      d[1] = (u32)f2bf(acc0[2]) | ((u32)f2bf(acc0[3]) << 16);
    }
    if (m < SUB - 16){
      u32* d = (u32*)(wrow + (size_t)(16 + m)*WSTR + i0);
      d[0] = (u32)f2bf(acc1[0]) | ((u32)f2bf(acc1[1]) << 16);
      d[1] = (u32)f2bf(acc1[2]) | ((u32)f2bf(acc1[3]) << 16);
    }
  }
}

// ---- K1: fused gather(window->LDS) + conv(MFMA, B from LDS) + mix/sigmoid epilogue ----
__global__ __launch_bounds__(512, 4) void k_mega(
    const float* __restrict__ S_e, const float* __restrict__ S_i,
    const float* __restrict__ Z, const u16* __restrict__ afrag,
    const u16* __restrict__ bfrag, const float* __restrict__ Cden,
    const float* __restrict__ Theta, float* __restrict__ out)
{
  __shared__ __align__(16) u16 win[3*SUB*WSTR];   // 56,640 B (window; reused for results/pbuf)
  __shared__ float lcden[SUB*SUB];
  __shared__ float lth[SUB];

  int tid = threadIdx.x;
  for (int i = tid; i < SUB*SUB; i += 512) lcden[i] = Cden[i];
  if (tid < SUB) lth[tid] = Theta[tid];

  // bijective XCD-aware chunk swizzle: consecutive chunks share an XCD L2
  int bid = blockIdx.x;
  int xcd = bid & 7, sb = bid >> 3;
  const int q8 = NCHUNKS_TOT >> 3, r8 = NCHUNKS_TOT & 7;   // 244, 2
  int c = (xcd < r8 ? xcd*(q8+1) : r8*(q8+1) + (xcd-r8)*q8) + sb;

  int wv = tid >> 6, lane = tid & 63;
  int m = lane & 15, kg = lane >> 4;
  long tw0 = (long)c*TCH - 200;                   // window global t start

  // ---- stage 1: gather windows (3 arrays x 20 ch x 464 t) into LDS ----
  stage1<200,7>(S_e, bfrag,                     win,                tw0, wv, lane);
  stage1<50, 2>(S_i, bfrag + 2*7*512,           win + SUB*WSTR,     tw0, wv, lane);
  stage1<20, 1>(Z,   bfrag + 2*7*512 + 2*2*512, win + 2*SUB*WSTR,   tw0, wv, lane);
  __syncthreads();                                // window ready

  // ---- stage 2: conv via MFMA, B-operands from LDS window ----
  int boffB = 16*m + 8*kg;                        // window-local element offset
  int toff  = 16*m + 4*kg;                        // C-tile t-offset
  f32x4 A0[5], A1[5];
  if (wv < 4){
    int ch0 = wv*5;
#pragma unroll
    for (int q = 0; q < 5; q++){
      int ch = ch0 + q;
      const u16* be = win + (size_t)(0*SUB + ch)*WSTR + boffB;
      const u16* bi = win + (size_t)(1*SUB + ch)*WSTR + boffB;
      const u16* ae = afrag + (size_t)((0*SUB + ch)*KKN)*512 + lane*8;
      const u16* ai = afrag + (size_t)((1*SUB + ch)*KKN)*512 + lane*8;
      f32x4 a = {0.f,0.f,0.f,0.f};
#pragma unroll
      for (int kk = 0; kk < KKN; kk++){
        a = __builtin_amdgcn_mfma_f32_16x16x32_bf16(
              *(const bf16x8*)(ae + kk*512), *(const bf16x8*)(be + 32*kk), a, 0,0,0);
        a = __builtin_amdgcn_mfma_f32_16x16x32_bf16(
              *(const bf16x8*)(ai + kk*512), *(const bf16x8*)(bi + 32*kk), a, 0,0,0);
      }
      A0[q] = a;
    }
  } else {
    int ch0 = (wv - 4)*5;
#pragma unroll
    for (int q = 0; q < 5; q++){
      int ch = ch0 + q;
      const u16* bz = win + (size_t)(2*SUB + ch)*WSTR + boffB;
      const u16* a2 = afrag + (size_t)((2*SUB + ch)*KKN)*512 + lane*8;
      const u16* a3 = afrag + (size_t)((3*SUB + ch)*KKN)*512 + lane*8;
      f32x4 s = {0.f,0.f,0.f,0.f}, h = {0.f,0.f,0.f,0.f};
#pragma unroll
      for (int kk = 0; kk < KKN; kk++){
        bf16x8 b = *(const bf16x8*)(bz + 32*kk);
        s = __builtin_amdgcn_mfma_f32_16x16x32_bf16(*(const bf16x8*)(a2 + kk*512), b, s, 0,0,0);
        h = __builtin_amdgcn_mfma_f32_16x16x32_bf16(*(const bf16x8*)(a3 + kk*512), b, h, 0,0,0);
      }
      A0[q] = s; A1[q] = h;
    }
  }
  __syncthreads();                                // all window reads complete

  // ---- write conv results into reused LDS: rows [syn0..19][spk0..19][hist0..19] ----
  u16* rr = win;
  if (wv < 4){
#pragma unroll
    for (int q = 0; q < 5; q++){
      int ch = wv*5 + q;
      u32* d = (u32*)(rr + ch*TCH + toff);
      d[0] = (u32)f2bf(A0[q][0]) | ((u32)f2bf(A0[q][1]) << 16);
      d[1] = (u32)f2bf(A0[q][2]) | ((u32)f2bf(A0[q][3]) << 16);
    }
  } else {
#pragma unroll
    for (int q = 0; q < 5; q++){
      int ch = (wv - 4)*5 + q;
      u32* d1 = (u32*)(rr + (SUB + ch)*TCH + toff);
      d1[0] = (u32)f2bf(A0[q][0]) | ((u32)f2bf(A0[q][1]) << 16);
      d1[1] = (u32)f2bf(A0[q][2]) | ((u32)f2bf(A0[q][3]) << 16);
      u32* d2 = (u32*)(rr + (2*SUB + ch)*TCH + toff);
      d2[0] = (u32)f2bf(A1[q][0]) | ((u32)f2bf(A1[q][1]) << 16);
      d2[1] = (u32)f2bf(A1[q][2]) | ((u32)f2bf(A1[q][3]) << 16);
    }
  }
  __syncthreads();

  // ---- epilogue: P = sigmoid(syn + theta + hist + Cden @ spk) ----
  float* pbuf = (float*)win;                      // [t*21 + sp] overlay after sync
  int t = tid >> 1, h = tid & 1;
  float spkv[SUB];
#pragma unroll
  for (int s = 0; s < SUB; s++) spkv[s] = bf2f(rr[(SUB + s)*TCH + t]);
  float res[10];
#pragma unroll
  for (int j = 0; j < 10; j++){
    int sp = h*10 + j;
    float msum = bf2f(rr[sp*TCH + t]) + lth[sp] + bf2f(rr[(2*SUB + sp)*TCH + t]);
#pragma unroll
    for (int s = 0; s < SUB; s++) msum += lcden[sp*SUB + s] * spkv[s];
    res[j] = 1.0f/(1.0f + expf(-msum));
  }
  __syncthreads();               // all rr reads complete before overlay
#pragma unroll
  for (int j = 0; j < 10; j++) pbuf[t*21 + h*10 + j] = res[j];
  __syncthreads();

  // ---- fully coalesced float4 copy-out ----
  int t0c = c*TCH;
  int tv = min(TCH, T_DATA - t0c);
  int np4 = tv*SUB/4;            // 20 % 4 == 0 -> no row crossing
  for (int i = tid; i < np4; i += 512){
    int p = i*4;
    int tt = p/20, sp = p - tt*20;
    float4 v;
    v.x = pbuf[tt*21 + sp];   v.y = pbuf[tt*21 + sp+1];
    v.z = pbuf[tt*21 + sp+2]; v.w = pbuf[tt*21 + sp+3];
    *(float4*)(out + (size_t)t0c*SUB + p) = v;
  }
}

extern "C" void kernel_launch(void* const* d_in, const int* in_sizes, int n_in,
                              void* d_out, int out_size, void* d_ws, size_t ws_size,
                              hipStream_t stream){
  const float* S_e  = (const float*)d_in[0];
  const float* S_i  = (const float*)d_in[1];
  const float* Z    = (const float*)d_in[2];
  const float* Cden = (const float*)d_in[3];
  const float* C_e  = (const float*)d_in[4];
  const float* C_i  = (const float*)d_in[5];
  const float* Tau  = (const float*)d_in[6];
  const float* Del  = (const float*)d_in[7];
  const float* Wsyn = (const float*)d_in[8];
  const float* Wspk = (const float*)d_in[9];
  const float* Whist= (const float*)d_in[10];
  const float* Theta= (const float*)d_in[11];
  float* out = (float*)d_out;

  // workspace: only afrag + bfrag now (~0.6 MB)
  u16* afrag = (u16*)d_ws;                         // 4*20*7*512 = 286720
  u16* bfrag = afrag + (size_t)4*SUB*KKN*512;      // 10240
  size_t need = ((size_t)4*SUB*KKN*512 + 10240) * 2;
  if (ws_size < need) return;

  k_setup<<<80 + 4*SUB*KKN + 40, 64, 0, stream>>>(
      Tau, Del, Wsyn, Wspk, Whist, C_e, C_i, out, afrag, bfrag);

  k_mega<<<NCHUNKS_TOT, 512, 0, stream>>>(
      S_e, S_i, Z, afrag, bfrag, Cden, Theta, out);
}